// Round 6
// baseline (441.454 us; speedup 1.0000x reference)
//
#include <hip/hip_runtime.h>
#include <math.h>
#include <string.h>

// V2VNetFusion on MI355X, round 10: fix the small-dispatch occupancy hole.
// Round-9 counters: CAND convs (275 blocks = 1 block/CU, 1 wave/SIMD) ran
// 82us each at MfmaUtil 4.7% / HBM 2.9% -- pure latency exposure; GATES
// (550 blocks = 2/CU) was ~5x healthier on the same kernel.  This round:
//  - CF template param: co-per-block 64 (CF=4) or 32 (CF=2).
//  - CAND and GATES-t0 run CF=2 -> 550-block grids -> 2 blocks/CU.
//  - CF=2 weights (9216 B/kb) double-buffer in the same 80384 B LDS
//    footprint -> ONE __syncthreads per kb; all DMAs (input+weights)
//    issued a full compute phase before the barrier that drains them.
//  - MSG / GATES-t>0 keep the proven round-9 CF=4 path unchanged.
//  - cf2 gates-update weight section aliases out[3]'s upper half
//    (dead until t=3 CAND writes it); ws layout unchanged.
#define HH 200
#define WW 352
#define HWSZ (HH*WW)          // 70400
#define CHW (64L*HWSZ)        // one (64,H,W) tensor, elems

enum { EPI_MSG=0, EPI_GATES=1, EPI_CAND=2 };

typedef __attribute__((ext_vector_type(8))) _Float16 f16x8;
typedef __attribute__((ext_vector_type(4))) float f32x4;
typedef __attribute__((ext_vector_type(4))) unsigned int uint4v;
typedef __attribute__((ext_vector_type(4))) unsigned short ushort4v;

__device__ __forceinline__ unsigned short f2h(float f) {
    _Float16 h = (_Float16)f;                    // v_cvt_f16_f32 (RTE)
    return __builtin_bit_cast(unsigned short, h);
}
__device__ __forceinline__ float h2f(unsigned short u) {
    return (float)__builtin_bit_cast(_Float16, u);
}

// global->LDS DMA, 16B per lane. LDS dest = wave-uniform base + lane*16.
__device__ __forceinline__ void load_lds16(const unsigned short* g,
                                           unsigned short* l) {
    __builtin_amdgcn_global_load_lds(
        (const __attribute__((address_space(1))) unsigned int*)g,
        (__attribute__((address_space(3))) unsigned int*)l, 16, 0, 0);
}

// Prepack conv weights to f16, LDS-ready lane-major layouts.
// CF=4 chunk: [sh(9)][cf(4)][lane(64)][8ch] = 18432 f16.
// CF=2 chunk: [sh(9)][cf(2)][lane(64)][8ch] =  9216 f16.
// lane = q*16+n16 -> co = co_off + cogrp*(CF*16) + cf*16+n16, ch = q*8+j.
// Sections: [0) msg cf4 (1x4) | [73728) gates cf4 (2x6) |
//           [294912) cand cf2 (2x6) | gatu: gates-update cf2 (2x6, co 64+)
//           -> separate base (aliases out[3] hi half) | zp: 128 zeros.
__global__ void prepack_k(const float* __restrict__ mw,
                          const float* __restrict__ gw,
                          const float* __restrict__ cw,
                          unsigned short* __restrict__ pw,
                          unsigned short* __restrict__ gatu,
                          unsigned short* __restrict__ zp)
{
    const int MSG_I  = 4*18432;       // 73728
    const int GAT_I  = 12*18432;      // 221184
    const int CAN_I  = 12*9216;       // 110592
    const int GATU_I = 12*9216;       // 110592
    const int TOTAL  = MSG_I + GAT_I + CAN_I + GATU_I;  // 516096
    int idx = blockIdx.x*256 + threadIdx.x;
    if (idx >= TOTAL) {
        int r = idx - TOTAL;
        if (r < 128) zp[r] = 0;
        return;
    }
    const float* w; int cin, nkb, CF, co_off, rel; unsigned short* base;
    if (idx < MSG_I) {
        w=mw; cin=128; nkb=4; CF=4; co_off=0;  rel=idx;                    base=pw;
    } else if (idx < MSG_I+GAT_I) {
        w=gw; cin=192; nkb=6; CF=4; co_off=0;  rel=idx-MSG_I;              base=pw+73728;
    } else if (idx < MSG_I+GAT_I+CAN_I) {
        w=cw; cin=192; nkb=6; CF=2; co_off=0;  rel=idx-MSG_I-GAT_I;        base=pw+294912;
    } else {
        w=gw; cin=192; nkb=6; CF=2; co_off=64; rel=idx-MSG_I-GAT_I-CAN_I;  base=gatu;
    }
    int per = CF*4608;                 // 18432 or 9216
    int chunk = rel / per, r = rel - chunk*per;
    int j = r & 7, lane = (r >> 3) & 63, cfsh = r >> 9;
    int cf = cfsh & (CF-1), sh = cfsh / CF;
    int q = lane >> 4, n16 = lane & 15;
    int co_l = cf*16 + n16, ch = q*8 + j;
    int cogrp = chunk / nkb, kb = chunk - cogrp*nkb;
    int co = co_off + cogrp*(CF*16) + co_l;
    float f = w[(((long)co)*cin + kb*32 + ch)*9 + sh];
    base[(size_t)chunk*per + r] = f2h(f);
}

// Convert x (2 agents x 4 t) fp32 planar -> f16 interleaved [t][half][pix][32].
__global__ void convert_all_k(const float* __restrict__ x,
                              unsigned short* __restrict__ xb0_all,
                              unsigned short* __restrict__ xb1_all)
{
    int idx = blockIdx.x*256 + threadIdx.x;      // 4,505,600 total
    int cp   = idx & 15;
    int rest = idx >> 4;
    int px4  = rest % 17600;
    int r2   = rest / 17600;                      // 0..15
    int hb = r2 & 1, ag = (r2 >> 1) & 1, t = r2 >> 2;
    const float* src = x + ((size_t)(ag*4 + t))*CHW
                         + (size_t)(hb*32 + 2*cp)*HWSZ + (size_t)px4*4;
    float4 a = *(const float4*)src;
    float4 b = *(const float4*)(src + HWSZ);
    unsigned int* dst = (unsigned int*)((ag ? xb1_all : xb0_all)
                        + (size_t)t*CHW + (size_t)hb*HWSZ*32) + (size_t)px4*64 + cp;
    dst[0]  = (unsigned)f2h(a.x) | ((unsigned)f2h(b.x) << 16);
    dst[16] = (unsigned)f2h(a.y) | ((unsigned)f2h(b.y) << 16);
    dst[32] = (unsigned)f2h(a.z) | ((unsigned)f2h(b.z) << 16);
    dst[48] = (unsigned)f2h(a.w) | ((unsigned)f2h(b.w) << 16);
}

// Block: (CF*16) out-ch x (8 rows x 32 cols), 256 thr = 4 waves; wave w =
// rows 2w,2w+1.  LDS: 2x input [10][34][32] f16 XOR-swz (21760 B) +
// weights 36864 B (CF=4: single 36-chunk buffer; CF=2: 2x 18-chunk dbuf)
// = 80384 B -> 2 blocks/CU.
// CF=4 loop: round-9 proven 2-barrier structure (weight DMA semi-exposed).
// CF=2 loop: full dbuf, ONE barrier per kb; every DMA flies across a
// whole compute phase before the barrier that drains it.
template<int EPI, int CF>
__global__ __launch_bounds__(256, 2)
void conv_mfma_k(const unsigned short* __restrict__ seg0b,
                 const unsigned short* __restrict__ seg1b,
                 const unsigned short* __restrict__ seg2b,
                 int nkb, int nkb_stride, int co_off,
                 const unsigned short* __restrict__ pw,
                 const unsigned short* __restrict__ zp,
                 const float* __restrict__ bias,
                 const unsigned short* e_hb,     // f16 interl. h_{t-1} (null @t=0)
                 const unsigned short* __restrict__ e_updb, // CAND: upd f16 interl.
                 float* out_f,                   // CAND: out[t] fp32 planar
                 unsigned short* out_b,          // MSG: aggb(t<3) GATES: rhb CAND: hb
                 unsigned short* out_b2)         // MSG: aggb3    GATES: updb
{
    __shared__ unsigned short s_in0[340*32];   // [pos=row*34+col][32ch] 21760 B
    __shared__ unsigned short s_in1[340*32];
    __shared__ unsigned short s_w[18432];      // CF4: 36 chunks; CF2: 2x18 dbuf

    const int tid  = threadIdx.x;
    const int lane = tid & 63;
    const int wv   = tid >> 6;                 // 0..3
    const int n16  = lane & 15;
    const int q    = lane >> 4;

    const int z = blockIdx.z;
    int grp, ts = 0;
    if (EPI == EPI_MSG) { ts = z; grp = 0; } else grp = z;

    const unsigned short* s0 = seg0b + (EPI==EPI_MSG ? (size_t)ts*CHW : 0);
    const unsigned short* s1 = seg1b + (EPI==EPI_MSG ? (size_t)ts*CHW : 0);
    unsigned short* ob = out_b;
    if (EPI == EPI_MSG) ob = (ts < 3) ? out_b + (size_t)ts*CHW : out_b2;

    const int x0p = blockIdx.x * 32;
    const int y0  = blockIdx.y * 8;

    // ---- halo descriptors: ring = 84 pos x 4 granules = 336 slots.
    int hdst0 = 0, hdst1 = 0; size_t hsrc0 = 0, hsrc1 = 0;
    bool hval0 = false, hval1 = false;
    {
        auto hcalc = [&](int s, int& hdst, size_t& hsrc, bool& hval) {
            int hp = s >> 2, gs = s & 3;
            int row, col;
            if (hp < 34)      { row = 0; col = hp; }
            else if (hp < 68) { row = 9; col = hp - 34; }
            else { int k = hp - 68; row = 1 + (k >> 1); col = (k & 1) * 33; }
            int pos = row*34 + col;
            int gy = y0 + row - 1, gx = x0p + col - 1;
            hdst = (pos << 5) + (gs << 3);
            int g = (gs ^ pos ^ (pos >> 2)) & 3;
            if ((unsigned)gy < (unsigned)HH && (unsigned)gx < (unsigned)WW) {
                hval = true;
                hsrc = ((size_t)(gy*WW + gx) << 5) + (size_t)(g << 3);
            }
        };
        if (tid < 336) hcalc(tid, hdst0, hsrc0, hval0);
        if (tid < 80)  hcalc(tid + 256, hdst1, hsrc1, hval1);
    }

    auto srcof = [&](int kb) -> const unsigned short* {
        return ((kb < 2) ? s0 : (kb < 4) ? s1 : seg2b) + (size_t)(kb & 1)*HWSZ*32;
    };

    struct HV { uint4v a, b; };
    auto halo_load = [&](int kb, HV& h) {
        const unsigned short* src = srcof(kb);
        if (tid < 336) h.a = *(const uint4v*)(hval0 ? src + hsrc0 : zp);
        if (tid < 80)  h.b = *(const uint4v*)(hval1 ? src + hsrc1 : zp);
    };
    auto halo_write = [&](unsigned short* bin, const HV& h) {
        if (tid < 336) *(uint4v*)&bin[hdst0] = h.a;
        if (tid < 80)  *(uint4v*)&bin[hdst1] = h.b;
    };

    // interior: 8 rows x 2 col-halves = 16 wave-chunks (full 64B granules,
    // inverse-swizzled source, linear LDS dest). Rows never OOB (8-row tile).
    auto stage_in = [&](int kb, unsigned short* bin) {
        const unsigned short* src = srcof(kb);
#pragma unroll
        for (int j = 0; j < 4; ++j) {
            const int c    = wv + 4*j;         // 0..15
            const int row  = 1 + (c >> 1);     // 1..8
            const int colh = c & 1;
            const int gy   = y0 + row - 1;     // in [0,199] always
            const int p0   = row*34 + 1 + colh*16;
            const int pl   = p0 + (lane >> 2);
            const int g    = ((lane & 3) ^ pl ^ (pl >> 2)) & 3;
            const int gx   = x0p + colh*16 + (lane >> 2);
            load_lds16(src + (((size_t)(gy*WW + gx)) << 5) + (g << 3),
                       &bin[(size_t)p0 << 5]);
        }
    };
    auto stage_w = [&](int kb, unsigned short* bw) {
        const unsigned short* wsrc = pw + (size_t)(grp*nkb_stride + kb)*(CF*4608);
        constexpr int NCH = (CF == 4) ? 36 : 18;
#pragma unroll
        for (int i = 0; i < (NCH + 3) / 4; ++i) {
            const int u = wv + 4*i;
            if (u < NCH)
                load_lds16(wsrc + (size_t)u*512 + (size_t)lane*8, &bw[(size_t)u*512]);
        }
    };

    f32x4 acc[CF][4];
#pragma unroll
    for (int cf=0; cf<CF; ++cf)
#pragma unroll
        for (int p=0; p<4; ++p) acc[cf][p] = (f32x4){0.f,0.f,0.f,0.f};

    auto compute = [&](const unsigned short* sin, const unsigned short* swt) {
#pragma unroll
        for (int ky = 0; ky < 3; ++ky) {
#pragma unroll
            for (int kx = 0; kx < 3; ++kx) {
                const int sh = ky*3 + kx;
                f16x8 aw[CF];
#pragma unroll
                for (int cf = 0; cf < CF; ++cf)
                    aw[cf] = *(const f16x8*)&swt[((sh*CF + cf)*64 + lane)*8];
#pragma unroll
                for (int p = 0; p < 4; ++p) {
                    const int rl = 2*wv + (p >> 1) + ky;
                    const int cl = 16*(p & 1) + n16 + kx;
                    const int pos = rl*34 + cl;
                    const int sw = (q ^ pos ^ (pos >> 2)) & 3;
                    f16x8 bfr = *(const f16x8*)&sin[(pos << 5) + (sw << 3)];
#pragma unroll
                    for (int cf = 0; cf < CF; ++cf)
                        acc[cf][p] = __builtin_amdgcn_mfma_f32_16x16x32_f16(
                                         aw[cf], bfr, acc[cf][p], 0, 0, 0);
                }
            }
        }
    };

    HV h0, h1;
    if constexpr (CF == 4) {
        // ---- round-9 proven 2-barrier loop, single weight buffer
        stage_in(0, s_in0);
        stage_w(0, s_w);
        halo_load(0, h0);
        for (int kb = 0; kb < nkb; kb += 2) {  // nkb even (4 or 6)
            halo_write(s_in0, h0);
            __syncthreads();
            halo_load(kb + 1, h1);
            stage_in(kb + 1, s_in1);
            __builtin_amdgcn_sched_barrier(0);
            compute(s_in0, s_w);
            __syncthreads();
            stage_w(kb + 1, s_w);
            halo_write(s_in1, h1);
            __syncthreads();
            if (kb + 2 < nkb) {
                halo_load(kb + 2, h0);
                stage_in(kb + 2, s_in0);
                __builtin_amdgcn_sched_barrier(0);
            }
            compute(s_in1, s_w);
            __syncthreads();
            if (kb + 2 < nkb) stage_w(kb + 2, s_w);
        }
    } else {
        // ---- CF=2: full double-buffer, ONE barrier per kb
        unsigned short* s_w0 = s_w;
        unsigned short* s_w1 = s_w + 9216;
        stage_in(0, s_in0); stage_w(0, s_w0); halo_load(0, h0);
        for (int kb = 0; kb < nkb; kb += 2) {  // nkb even (4 or 6)
            halo_write(s_in0, h0);             // waits h0 (vmcnt dep)
            __syncthreads();                   // drains kb DMAs
            stage_in(kb + 1, s_in1); stage_w(kb + 1, s_w1); halo_load(kb + 1, h1);
            __builtin_amdgcn_sched_barrier(0);
            compute(s_in0, s_w0);
            halo_write(s_in1, h1);
            __syncthreads();                   // drains kb+1 DMAs (flew over compute)
            if (kb + 2 < nkb) {
                stage_in(kb + 2, s_in0); stage_w(kb + 2, s_w0); halo_load(kb + 2, h0);
                __builtin_amdgcn_sched_barrier(0);
            }
            compute(s_in1, s_w1);
        }
    }

    // ---- epilogue. C/D: pixel = lane&15, co = (lane>>4)*4 + reg
#pragma unroll
    for (int cf = 0; cf < CF; ++cf) {
        const int co_r0 = co_off + grp*(CF*16) + cf*16 + q*4;  // global co of reg 0
        const int half  = (co_r0 >> 5) & 1;
        const int cmod  = co_r0 & 31;
#pragma unroll
        for (int p = 0; p < 4; ++p) {
            const int row = y0 + 2*wv + (p >> 1);
            const int col = x0p + 16*(p & 1) + n16;
            if (row >= HH) continue;
            const long pix = (long)row*WW + col;
            const size_t iidx = (((size_t)half*HWSZ + pix) << 5) + cmod;
            float v[4];
#pragma unroll
            for (int r = 0; r < 4; ++r) v[r] = acc[cf][p][r] + bias[co_r0 + r];

            if (EPI == EPI_MSG) {
                ushort4v xv = *(const ushort4v*)&s0[iidx];
                ushort4v s;
#pragma unroll
                for (int r = 0; r < 4; ++r)
                    s[r] = f2h(0.5f*(h2f(xv[r]) + v[r]));
                *(ushort4v*)&ob[iidx] = s;
            } else if (EPI == EPI_GATES) {
                if (co_r0 < 64) {   // reset -> rh = sigmoid * h (f16 interl.)
                    ushort4v hv = e_hb ? *(const ushort4v*)&e_hb[iidx]
                                       : (ushort4v){0,0,0,0};
                    ushort4v s;
#pragma unroll
                    for (int r = 0; r < 4; ++r) {
                        float g = 1.f/(1.f + __expf(-v[r]));
                        s[r] = f2h(g * h2f(hv[r]));
                    }
                    *(ushort4v*)&out_b[iidx] = s;
                } else {            // update -> updb (f16 interleaved)
                    const int cu = co_r0 - 64;
                    const size_t uidx = (((size_t)(cu >> 5)*HWSZ + pix) << 5) + (cu & 31);
                    ushort4v s;
#pragma unroll
                    for (int r = 0; r < 4; ++r)
                        s[r] = f2h(1.f/(1.f + __expf(-v[r])));
                    *(ushort4v*)&out_b2[uidx] = s;
                }
            } else {                // CAND: h_next -> out fp32 planar + hb f16
                ushort4v uv = *(const ushort4v*)&e_updb[iidx];
                ushort4v hv = e_hb ? *(const ushort4v*)&e_hb[iidx]
                                   : (ushort4v){0,0,0,0};
                ushort4v s;
#pragma unroll
                for (int r = 0; r < 4; ++r) {
                    float cnm = tanhf(v[r]);
                    float u   = h2f(uv[r]);
                    float hn  = (1.f - u)*h2f(hv[r]) + u*cnm;
                    out_f[(long)(co_r0 + r)*HWSZ + pix] = hn;
                    s[r] = f2h(hn);
                }
                *(ushort4v*)&out_b[iidx] = s;
            }
        }
    }
}

// ws (u16 units): xb0_all 4C | aggb3 C | rhb C | updb C | hb C | pw 405504
//   | zp 128  = 72.9 MB.   d_out aliases: xb1_all = out[0..1] (dead until
//   step 0 writes out[0]), aggb[0..2] = out[2..3], pw_gatu = out[3] upper
//   half (dead until t=3 CAND; used only at t=0 GATES).
extern "C" void kernel_launch(void* const* d_in, const int* in_sizes, int n_in,
                              void* d_out, int out_size, void* d_ws, size_t ws_size,
                              hipStream_t stream)
{
    const float* x       = (const float*)d_in[0];
    const float* msg_w   = (const float*)d_in[1];
    const float* msg_b   = (const float*)d_in[2];
    const float* gates_w = (const float*)d_in[3];
    const float* gates_b = (const float*)d_in[4];
    const float* can_w   = (const float*)d_in[5];
    const float* can_b   = (const float*)d_in[6];
    float* out = (float*)d_out;

    unsigned short* W       = (unsigned short*)d_ws;
    unsigned short* xb0_all = W;                  // [4][2][HWSZ][32]
    unsigned short* aggb3   = W + 4*CHW;
    unsigned short* rhb     = W + 5*CHW;
    unsigned short* updb    = W + 6*CHW;
    unsigned short* hb      = W + 7*CHW;
    unsigned short* pw      = W + 8*CHW;          // 405504 u16
    unsigned short* pw_msg  = pw;                 // cf4 msg
    unsigned short* pw_gat  = pw + 73728;         // cf4 gates
    unsigned short* pw_can  = pw + 294912;        // cf2 cand
    unsigned short* zp      = pw + 405504;        // 128 u16 zero page

    unsigned short* outU16   = (unsigned short*)d_out;
    unsigned short* xb1_all  = outU16;            // 4*CHW u16 = out[0..1]
    unsigned short* aggbase  = outU16 + 4*CHW;    // aggb[0..2] = out[2..3]
    unsigned short* pw_gatu  = outU16 + 7*CHW;    // cf2 gates-update (t=0 only)

    prepack_k<<<dim3(2017), dim3(256), 0, stream>>>(msg_w, gates_w, can_w,
                                                    pw, pw_gatu, zp);
    convert_all_k<<<dim3(17600), dim3(256), 0, stream>>>(x, xb0_all, xb1_all);

    // msg for all 4 t in one dispatch: Cin=[x0|x1], Cout=64 -> aggb[t]
    conv_mfma_k<EPI_MSG,4><<<dim3(11,25,4), dim3(256), 0, stream>>>(
        xb0_all, xb1_all, nullptr, 4, 4, 0, pw_msg, zp, msg_b,
        nullptr, nullptr, nullptr, aggbase, aggb3);

    for (int t = 0; t < 4; ++t) {
        const unsigned short* xt  = xb0_all + (size_t)t*CHW;
        const unsigned short* agt = (t < 3) ? aggbase + (size_t)t*CHW : aggb3;
        const unsigned short* hprev = t ? hb : nullptr;

        if (t == 0) {
            // t=0: h==0 -> reset*h==0 and CAND(nkb=4) never reads rhb;
            // launch only the update half, CF=2 -> 550 blocks (2/CU).
            conv_mfma_k<EPI_GATES,2><<<dim3(11,25,2), dim3(256), 0, stream>>>(
                xt, agt, nullptr, 4, 6, 64, pw_gatu, zp, gates_b,
                nullptr, nullptr, nullptr, rhb, updb);
        } else {
            // gates: Cin=[x|agg|h], Cout=128; z=0 reset / z=1 update (CF=4).
            conv_mfma_k<EPI_GATES,4><<<dim3(11,25,2), dim3(256), 0, stream>>>(
                xt, agt, hb, 6, 6, 0, pw_gat, zp, gates_b,
                hprev, nullptr, nullptr, rhb, updb);
        }
        // cand: Cin=[x|agg|rh], Cout=64 -> out[t] fp32 + hb f16; CF=2 ->
        // 550 blocks (2/CU); z in {0,1} covers co 0..31 / 32..63.
        conv_mfma_k<EPI_CAND,2><<<dim3(11,25,2), dim3(256), 0, stream>>>(
            xt, agt, rhb, t ? 6 : 4, 6, 0, pw_can, zp, can_b,
            hprev, updb, out + (size_t)t*CHW, hb, nullptr);
    }
}

// Round 7
// 422.661 us; speedup vs baseline: 1.0445x; 1.0445x over previous
//
#include <hip/hip_runtime.h>
#include <math.h>
#include <string.h>

// V2VNetFusion on MI355X, round 11: max-occupancy single-buffered CF=2.
// Cross-round scaling law: 4 waves/CU -> 190 TF, 8 waves/CU -> ~450 TF
// (r9/r10); latency-bound, ~4x above the LDS-issue floor. The binding
// constraint is resident waves, capped by LDS footprint. At high
// occupancy TLP hides staging latency (T14-null regime), so LDS spent
// on double-buffering is wasted. This round:
//  - CF=2 everywhere (32 co/block), SINGLE-buffered input + weights:
//    LDS = 21760 + 9216 = 30976 B -> 4-5 blocks/CU (16-20 waves).
//  - Staging latency exposed per kb between 2 barriers; covered by TLP.
//  - grp folded into blockIdx.x parity: co-twins dispatch-adjacent ->
//    L2 input-tile sharing.  Grids: MSG 2200, GATES 1100, CAND 550.
//  - Uniform CF=2 weight layout; GATES-t0 update half = grp 2,3 of the
//    standard gates section (no special section).
#define HH 200
#define WW 352
#define HWSZ (HH*WW)          // 70400
#define CHW (64L*HWSZ)        // one (64,H,W) tensor, elems

enum { EPI_MSG=0, EPI_GATES=1, EPI_CAND=2 };

typedef __attribute__((ext_vector_type(8))) _Float16 f16x8;
typedef __attribute__((ext_vector_type(4))) float f32x4;
typedef __attribute__((ext_vector_type(4))) unsigned int uint4v;
typedef __attribute__((ext_vector_type(4))) unsigned short ushort4v;

__device__ __forceinline__ unsigned short f2h(float f) {
    _Float16 h = (_Float16)f;                    // v_cvt_f16_f32 (RTE)
    return __builtin_bit_cast(unsigned short, h);
}
__device__ __forceinline__ float h2f(unsigned short u) {
    return (float)__builtin_bit_cast(_Float16, u);
}

// global->LDS DMA, 16B per lane. LDS dest = wave-uniform base + lane*16.
__device__ __forceinline__ void load_lds16(const unsigned short* g,
                                           unsigned short* l) {
    __builtin_amdgcn_global_load_lds(
        (const __attribute__((address_space(1))) unsigned int*)g,
        (__attribute__((address_space(3))) unsigned int*)l, 16, 0, 0);
}

// Prepack conv weights to f16, LDS-ready lane-major CF=2 layout:
// chunk(cogrp32,kb) = [sh(9)][cf(2)][lane(64)][8ch] = 9216 f16.
// lane = q*16+n16 -> co = cogrp*32 + cf*16+n16, ch = q*8+j.
// Sections: msg 2x4 @0 | gates 4x6 @73728 | cand 2x6 @294912 | zp 128.
__global__ void prepack_k(const float* __restrict__ mw,
                          const float* __restrict__ gw,
                          const float* __restrict__ cw,
                          unsigned short* __restrict__ pw,
                          unsigned short* __restrict__ zp)
{
    const int MSG_I = 8*9216;         // 73728
    const int GAT_I = 24*9216;        // 221184
    const int CAN_I = 12*9216;        // 110592
    const int TOTAL = MSG_I + GAT_I + CAN_I;   // 405504
    int idx = blockIdx.x*256 + threadIdx.x;
    if (idx >= TOTAL) {
        int r = idx - TOTAL;
        if (r < 128) zp[r] = 0;
        return;
    }
    const float* w; int cin, nkb, rel; unsigned short* base;
    if (idx < MSG_I)              { w=mw; cin=128; nkb=4; rel=idx;             base=pw; }
    else if (idx < MSG_I+GAT_I)   { w=gw; cin=192; nkb=6; rel=idx-MSG_I;       base=pw+73728; }
    else                          { w=cw; cin=192; nkb=6; rel=idx-MSG_I-GAT_I; base=pw+294912; }
    int chunk = rel / 9216, r = rel - chunk*9216;
    int j = r & 7, lane = (r >> 3) & 63, cfsh = r >> 9;   // 0..17
    int cf = cfsh & 1, sh = cfsh >> 1;
    int q = lane >> 4, n16 = lane & 15;
    int co_l = cf*16 + n16, ch = q*8 + j;
    int cogrp = chunk / nkb, kb = chunk - cogrp*nkb;
    float f = w[(((long)(cogrp*32 + co_l))*cin + kb*32 + ch)*9 + sh];
    base[(size_t)chunk*9216 + r] = f2h(f);
}

// Convert x (2 agents x 4 t) fp32 planar -> f16 interleaved [t][half][pix][32].
__global__ void convert_all_k(const float* __restrict__ x,
                              unsigned short* __restrict__ xb0_all,
                              unsigned short* __restrict__ xb1_all)
{
    int idx = blockIdx.x*256 + threadIdx.x;      // 4,505,600 total
    int cp   = idx & 15;
    int rest = idx >> 4;
    int px4  = rest % 17600;
    int r2   = rest / 17600;                      // 0..15
    int hb = r2 & 1, ag = (r2 >> 1) & 1, t = r2 >> 2;
    const float* src = x + ((size_t)(ag*4 + t))*CHW
                         + (size_t)(hb*32 + 2*cp)*HWSZ + (size_t)px4*4;
    float4 a = *(const float4*)src;
    float4 b = *(const float4*)(src + HWSZ);
    unsigned int* dst = (unsigned int*)((ag ? xb1_all : xb0_all)
                        + (size_t)t*CHW + (size_t)hb*HWSZ*32) + (size_t)px4*64 + cp;
    dst[0]  = (unsigned)f2h(a.x) | ((unsigned)f2h(b.x) << 16);
    dst[16] = (unsigned)f2h(a.y) | ((unsigned)f2h(b.y) << 16);
    dst[32] = (unsigned)f2h(a.z) | ((unsigned)f2h(b.z) << 16);
    dst[48] = (unsigned)f2h(a.w) | ((unsigned)f2h(b.w) << 16);
}

// Block: 32 out-ch x (8 rows x 32 cols), 256 thr = 4 waves; wave w = rows
// 2w,2w+1.  LDS: input [10][34][32] f16 XOR-swz (21760 B) + weights
// [9][2][64][8] (9216 B) = 30976 B -> 4-5 blocks/CU.
// Per kb: [halo_load(kb+1) | compute(kb)] sync [stage kb+1 DMAs +
// halo_write] sync.  Staging latency exposed per block, hidden by the
// 3-4 co-resident blocks (TLP).
// blockIdx.x = tile_x*2 + grp_lo (co-twins adjacent for L2 sharing).
template<int EPI>
__global__ __launch_bounds__(256, 4)
void conv_mfma_k(const unsigned short* __restrict__ seg0b,
                 const unsigned short* __restrict__ seg1b,
                 const unsigned short* __restrict__ seg2b,
                 int nkb, int nkb_stride, int grp_base,
                 const unsigned short* __restrict__ pw,
                 const unsigned short* __restrict__ zp,
                 const float* __restrict__ bias,
                 const unsigned short* e_hb,     // f16 interl. h_{t-1} (null @t=0)
                 const unsigned short* __restrict__ e_updb, // CAND: upd f16 interl.
                 float* out_f,                   // CAND: out[t] fp32 planar
                 unsigned short* out_b,          // MSG: aggb(t<3) GATES: rhb CAND: hb
                 unsigned short* out_b2)         // MSG: aggb3    GATES: updb
{
    __shared__ unsigned short s_in[340*32];    // [pos=row*34+col][32ch] 21760 B
    __shared__ unsigned short s_w[9*2*64*8];   // [sh][cf][lane][8]      9216 B

    const int tid  = threadIdx.x;
    const int lane = tid & 63;
    const int wv   = tid >> 6;                 // 0..3
    const int n16  = lane & 15;
    const int q    = lane >> 4;

    int grp, ts = 0;
    if (EPI == EPI_MSG) { ts = blockIdx.z; grp = blockIdx.x & 1; }
    else                { grp = (blockIdx.x & 1) + 2*blockIdx.z + grp_base; }

    const unsigned short* s0 = seg0b + (EPI==EPI_MSG ? (size_t)ts*CHW : 0);
    const unsigned short* s1 = seg1b + (EPI==EPI_MSG ? (size_t)ts*CHW : 0);
    unsigned short* ob = out_b;
    if (EPI == EPI_MSG) ob = (ts < 3) ? out_b + (size_t)ts*CHW : out_b2;

    const int x0p = (blockIdx.x >> 1) * 32;
    const int y0  = blockIdx.y * 8;

    // ---- halo descriptors: ring = 84 pos x 4 granules = 336 slots.
    int hdst0 = 0, hdst1 = 0; size_t hsrc0 = 0, hsrc1 = 0;
    bool hval0 = false, hval1 = false;
    {
        auto hcalc = [&](int s, int& hdst, size_t& hsrc, bool& hval) {
            int hp = s >> 2, gs = s & 3;
            int row, col;
            if (hp < 34)      { row = 0; col = hp; }
            else if (hp < 68) { row = 9; col = hp - 34; }
            else { int k = hp - 68; row = 1 + (k >> 1); col = (k & 1) * 33; }
            int pos = row*34 + col;
            int gy = y0 + row - 1, gx = x0p + col - 1;
            hdst = (pos << 5) + (gs << 3);
            int g = (gs ^ pos ^ (pos >> 2)) & 3;
            if ((unsigned)gy < (unsigned)HH && (unsigned)gx < (unsigned)WW) {
                hval = true;
                hsrc = ((size_t)(gy*WW + gx) << 5) + (size_t)(g << 3);
            }
        };
        if (tid < 336) hcalc(tid, hdst0, hsrc0, hval0);
        if (tid < 80)  hcalc(tid + 256, hdst1, hsrc1, hval1);
    }

    auto srcof = [&](int kb) -> const unsigned short* {
        return ((kb < 2) ? s0 : (kb < 4) ? s1 : seg2b) + (size_t)(kb & 1)*HWSZ*32;
    };

    struct HV { uint4v a, b; };
    auto halo_load = [&](int kb, HV& h) {
        const unsigned short* src = srcof(kb);
        if (tid < 336) h.a = *(const uint4v*)(hval0 ? src + hsrc0 : zp);
        if (tid < 80)  h.b = *(const uint4v*)(hval1 ? src + hsrc1 : zp);
    };
    auto halo_write = [&](const HV& h) {
        if (tid < 336) *(uint4v*)&s_in[hdst0] = h.a;
        if (tid < 80)  *(uint4v*)&s_in[hdst1] = h.b;
    };

    // interior: 8 rows x 2 col-halves = 16 wave-chunks (full 64B granules,
    // inverse-swizzled source, linear LDS dest). Rows never OOB (8-row tile).
    auto stage_in = [&](int kb) {
        const unsigned short* src = srcof(kb);
#pragma unroll
        for (int j = 0; j < 4; ++j) {
            const int c    = wv + 4*j;         // 0..15
            const int row  = 1 + (c >> 1);     // 1..8
            const int colh = c & 1;
            const int gy   = y0 + row - 1;     // in [0,199] always
            const int p0   = row*34 + 1 + colh*16;
            const int pl   = p0 + (lane >> 2);
            const int g    = ((lane & 3) ^ pl ^ (pl >> 2)) & 3;
            const int gx   = x0p + colh*16 + (lane >> 2);
            load_lds16(src + (((size_t)(gy*WW + gx)) << 5) + (g << 3),
                       &s_in[(size_t)p0 << 5]);
        }
    };
    auto stage_w = [&](int kb) {
        const unsigned short* wsrc = pw + (size_t)(grp*nkb_stride + kb)*9216;
#pragma unroll
        for (int i = 0; i < 5; ++i) {
            const int u = wv + 4*i;            // 0..19, skip >=18
            if (u < 18)
                load_lds16(wsrc + (size_t)u*512 + (size_t)lane*8, &s_w[(size_t)u*512]);
        }
    };

    f32x4 acc[2][4];
#pragma unroll
    for (int cf=0; cf<2; ++cf)
#pragma unroll
        for (int p=0; p<4; ++p) acc[cf][p] = (f32x4){0.f,0.f,0.f,0.f};

    auto compute = [&]() {
#pragma unroll
        for (int ky = 0; ky < 3; ++ky) {
#pragma unroll
            for (int kx = 0; kx < 3; ++kx) {
                const int sh = ky*3 + kx;
                f16x8 aw0 = *(const f16x8*)&s_w[((sh*2 + 0)*64 + lane)*8];
                f16x8 aw1 = *(const f16x8*)&s_w[((sh*2 + 1)*64 + lane)*8];
#pragma unroll
                for (int p = 0; p < 4; ++p) {
                    const int rl = 2*wv + (p >> 1) + ky;
                    const int cl = 16*(p & 1) + n16 + kx;
                    const int pos = rl*34 + cl;
                    const int sw = (q ^ pos ^ (pos >> 2)) & 3;
                    f16x8 bfr = *(const f16x8*)&s_in[(pos << 5) + (sw << 3)];
                    acc[0][p] = __builtin_amdgcn_mfma_f32_16x16x32_f16(aw0, bfr, acc[0][p], 0, 0, 0);
                    acc[1][p] = __builtin_amdgcn_mfma_f32_16x16x32_f16(aw1, bfr, acc[1][p], 0, 0, 0);
                }
            }
        }
    };

    // ---- prologue: stage kb=0 fully (exposed once; TLP covers)
    HV h;
    stage_in(0); stage_w(0); halo_load(0, h);
    halo_write(h);               // ds_write waits its vmcnt deps
    __syncthreads();             // DMAs drained + halo visible

    for (int kb = 0; kb < nkb; ++kb) {
        if (kb + 1 < nkb) halo_load(kb + 1, h);   // flies over compute
        compute();
        __syncthreads();         // all waves done reading s_in/s_w
        if (kb + 1 < nkb) {
            stage_in(kb + 1); stage_w(kb + 1);
            halo_write(h);
            __syncthreads();     // kb+1 DMAs drained + halo visible
        }
    }

    // ---- epilogue. C/D: pixel = lane&15, co = (lane>>4)*4 + reg
#pragma unroll
    for (int cf = 0; cf < 2; ++cf) {
        const int co_r0 = grp*32 + cf*16 + q*4;    // global co of reg 0
        const int half  = (co_r0 >> 5) & 1;
        const int cmod  = co_r0 & 31;
#pragma unroll
        for (int p = 0; p < 4; ++p) {
            const int row = y0 + 2*wv + (p >> 1);
            const int col = x0p + 16*(p & 1) + n16;
            if (row >= HH) continue;
            const long pix = (long)row*WW + col;
            const size_t iidx = (((size_t)half*HWSZ + pix) << 5) + cmod;
            float v[4];
#pragma unroll
            for (int r = 0; r < 4; ++r) v[r] = acc[cf][p][r] + bias[co_r0 + r];

            if (EPI == EPI_MSG) {
                ushort4v xv = *(const ushort4v*)&s0[iidx];
                ushort4v s;
#pragma unroll
                for (int r = 0; r < 4; ++r)
                    s[r] = f2h(0.5f*(h2f(xv[r]) + v[r]));
                *(ushort4v*)&ob[iidx] = s;
            } else if (EPI == EPI_GATES) {
                if (co_r0 < 64) {   // reset -> rh = sigmoid * h (f16 interl.)
                    ushort4v hv = e_hb ? *(const ushort4v*)&e_hb[iidx]
                                       : (ushort4v){0,0,0,0};
                    ushort4v s;
#pragma unroll
                    for (int r = 0; r < 4; ++r) {
                        float g = 1.f/(1.f + __expf(-v[r]));
                        s[r] = f2h(g * h2f(hv[r]));
                    }
                    *(ushort4v*)&out_b[iidx] = s;
                } else {            // update -> updb (f16 interleaved)
                    const int cu = co_r0 - 64;
                    const size_t uidx = (((size_t)(cu >> 5)*HWSZ + pix) << 5) + (cu & 31);
                    ushort4v s;
#pragma unroll
                    for (int r = 0; r < 4; ++r)
                        s[r] = f2h(1.f/(1.f + __expf(-v[r])));
                    *(ushort4v*)&out_b2[uidx] = s;
                }
            } else {                // CAND: h_next -> out fp32 planar + hb f16
                ushort4v uv = *(const ushort4v*)&e_updb[iidx];
                ushort4v hv = e_hb ? *(const ushort4v*)&e_hb[iidx]
                                   : (ushort4v){0,0,0,0};
                ushort4v s;
#pragma unroll
                for (int r = 0; r < 4; ++r) {
                    float cnm = tanhf(v[r]);
                    float u   = h2f(uv[r]);
                    float hn  = (1.f - u)*h2f(hv[r]) + u*cnm;
                    out_f[(long)(co_r0 + r)*HWSZ + pix] = hn;
                    s[r] = f2h(hn);
                }
                *(ushort4v*)&out_b[iidx] = s;
            }
        }
    }
}

// ws (u16 units): xb0_all 4C | aggb3 C | rhb C | updb C | hb C | pw 405504
//   | zp 128  = 72.9 MB.   d_out aliases: xb1_all = out[0..1] (dead until
//   step 0 writes out[0]), aggb[0..2] = out[2..3].
extern "C" void kernel_launch(void* const* d_in, const int* in_sizes, int n_in,
                              void* d_out, int out_size, void* d_ws, size_t ws_size,
                              hipStream_t stream)
{
    const float* x       = (const float*)d_in[0];
    const float* msg_w   = (const float*)d_in[1];
    const float* msg_b   = (const float*)d_in[2];
    const float* gates_w = (const float*)d_in[3];
    const float* gates_b = (const float*)d_in[4];
    const float* can_w   = (const float*)d_in[5];
    const float* can_b   = (const float*)d_in[6];
    float* out = (float*)d_out;

    unsigned short* W       = (unsigned short*)d_ws;
    unsigned short* xb0_all = W;                  // [4][2][HWSZ][32]
    unsigned short* aggb3   = W + 4*CHW;
    unsigned short* rhb     = W + 5*CHW;
    unsigned short* updb    = W + 6*CHW;
    unsigned short* hb      = W + 7*CHW;
    unsigned short* pw      = W + 8*CHW;          // 405504 u16
    unsigned short* pw_msg  = pw;                 // cf2 msg   (2x4)
    unsigned short* pw_gat  = pw + 73728;         // cf2 gates (4x6)
    unsigned short* pw_can  = pw + 294912;        // cf2 cand  (2x6)
    unsigned short* zp      = pw + 405504;        // 128 u16 zero page

    unsigned short* outU16   = (unsigned short*)d_out;
    unsigned short* xb1_all  = outU16;            // 4*CHW u16 = out[0..1]
    unsigned short* aggbase  = outU16 + 4*CHW;    // aggb[0..2] = out[2..3]

    prepack_k<<<dim3(1585), dim3(256), 0, stream>>>(msg_w, gates_w, can_w, pw, zp);
    convert_all_k<<<dim3(17600), dim3(256), 0, stream>>>(x, xb0_all, xb1_all);

    // msg for all 4 t in one dispatch: Cin=[x0|x1], Cout=64 -> aggb[t].
    // grid x = tile_x*2 + grp (co-twins adjacent), z = t: 2200 blocks.
    conv_mfma_k<EPI_MSG><<<dim3(22,25,4), dim3(256), 0, stream>>>(
        xb0_all, xb1_all, nullptr, 4, 4, 0, pw_msg, zp, msg_b,
        nullptr, nullptr, nullptr, aggbase, aggb3);

    for (int t = 0; t < 4; ++t) {
        const unsigned short* xt  = xb0_all + (size_t)t*CHW;
        const unsigned short* agt = (t < 3) ? aggbase + (size_t)t*CHW : aggb3;
        const unsigned short* hprev = t ? hb : nullptr;

        if (t == 0) {
            // t=0: h==0 -> reset*h==0 and CAND(nkb=4) never reads rhb;
            // update half only: grp = 2 + (bx&1), nkb=4. 550 blocks.
            conv_mfma_k<EPI_GATES><<<dim3(22,25,1), dim3(256), 0, stream>>>(
                xt, agt, nullptr, 4, 6, 2, pw_gat, zp, gates_b,
                nullptr, nullptr, nullptr, rhb, updb);
        } else {
            // gates: Cin=[x|agg|h], Cout=128; grp = (bx&1)+2z in 0..3.
            // 1100 blocks.
            conv_mfma_k<EPI_GATES><<<dim3(22,25,2), dim3(256), 0, stream>>>(
                xt, agt, hb, 6, 6, 0, pw_gat, zp, gates_b,
                hprev, nullptr, nullptr, rhb, updb);
        }
        // cand: Cin=[x|agg|rh], Cout=64 -> out[t] fp32 + hb f16.
        // grp = bx&1 in {0,1}: 550 blocks.
        conv_mfma_k<EPI_CAND><<<dim3(22,25,1), dim3(256), 0, stream>>>(
            xt, agt, rhb, t ? 6 : 4, 6, 0, pw_can, zp, can_b,
            hprev, updb, out + (size_t)t*CHW, hb, nullptr);
    }
}